// Round 2
// baseline (579.876 us; speedup 1.0000x reference)
//
#include <hip/hip_runtime.h>
#include <hip/hip_bf16.h>

// ---------------- problem constants ----------------
#define B_SZ   8192
#define XD     362
#define NEXP   3
#define NTILES 70          // 128-row tile capacity (segments 256-aligned)
#define MP     (NTILES*128)

typedef __bf16 bf16x8 __attribute__((ext_vector_type(8)));
typedef float  f32x4  __attribute__((ext_vector_type(4)));

__device__ __forceinline__ unsigned short f2bf(float f) {
    unsigned u = __float_as_uint(f);
    u += 0x7fffu + ((u >> 16) & 1u);
    return (unsigned short)(u >> 16);
}

// hdr: [0..2]=counts, [6..8]=seg_start_row, [12]=total 128-tiles,
// [13]=last 256-tile index (nt/2-1), [16]=float accumulator,
// [32..101]=128-tile -> expert (-1 = inactive)
__global__ __launch_bounds__(1024) void k_route(const int* __restrict__ a,
                                                int* __restrict__ hdr,
                                                int* __restrict__ row_of) {
    __shared__ int sc[3][1024];
    int tid = threadIdx.x;
    int ev[8];
    int c0 = 0, c1 = 0, c2 = 0;
#pragma unroll
    for (int j = 0; j < 8; ++j) {
        int e = a[tid * 8 + j];
        ev[j] = e;
        c0 += (e == 0); c1 += (e == 1); c2 += (e == 2);
    }
    sc[0][tid] = c0; sc[1][tid] = c1; sc[2][tid] = c2;
    __syncthreads();
    for (int off = 1; off < 1024; off <<= 1) {
        int v0 = (tid >= off) ? sc[0][tid - off] : 0;
        int v1 = (tid >= off) ? sc[1][tid - off] : 0;
        int v2 = (tid >= off) ? sc[2][tid - off] : 0;
        __syncthreads();
        sc[0][tid] += v0; sc[1][tid] += v1; sc[2][tid] += v2;
        __syncthreads();
    }
    int tot0 = sc[0][1023], tot1 = sc[1][1023], tot2 = sc[2][1023];
    int t0 = ((tot0 + 255) >> 8) << 1;   // 128-tiles per expert, 256-aligned
    int t1 = ((tot1 + 255) >> 8) << 1;
    int t2 = ((tot2 + 255) >> 8) << 1;
    int seg0 = 0, seg1 = t0 * 128, seg2 = (t0 + t1) * 128;
    int nt = t0 + t1 + t2;
    int b0 = seg0 + sc[0][tid] - c0;
    int b1 = seg1 + sc[1][tid] - c1;
    int b2 = seg2 + sc[2][tid] - c2;
#pragma unroll
    for (int j = 0; j < 8; ++j) {
        int e = ev[j];
        int pos = (e == 0) ? b0++ : (e == 1) ? b1++ : b2++;
        row_of[pos] = tid * 8 + j;
    }
    if (tid == 0) {
        hdr[0] = tot0; hdr[1] = tot1; hdr[2] = tot2;
        hdr[6] = seg0; hdr[7] = seg1; hdr[8] = seg2;
        hdr[12] = nt;
        hdr[13] = nt / 2 - 1;     // last 256-row tile index
        hdr[16] = 0;
    }
    if (tid < NTILES)
        hdr[32 + tid] = (tid < t0) ? 0 : (tid < t0 + t1) ? 1 : (tid < nt) ? 2 : -1;
    for (int r = tid; r < MP; r += 1024) {
        int pad;
        if (r < seg1)           pad = (r - seg0) >= tot0;
        else if (r < seg2)      pad = (r - seg1) >= tot1;
        else if (r < nt * 128)  pad = (r - seg2) >= tot2;
        else                    pad = 1;
        if (pad) row_of[r] = -1;
    }
}

__global__ void k_gather(const float* __restrict__ x, const int* __restrict__ row_of,
                         unsigned short* __restrict__ xg) {
    int r = blockIdx.x;
    int c = threadIdx.x;
    int orig = row_of[r];
    float v = (orig >= 0 && c < XD) ? x[(size_t)orig * XD + c] : 0.f;
    xg[(size_t)r * 384 + c] = f2bf(v);
}

// ---------------- weight transpose+convert: W[e](K,N) f32 -> Wt[e](Np,Kp) bf16 ----------------
__global__ void k_transpose(const float* __restrict__ W, unsigned short* __restrict__ Wt,
                            int K, int N, int Kp, int Np) {
    __shared__ float t[64][33];
    int e  = blockIdx.z;
    int kb = blockIdx.x * 64, nb = blockIdx.y * 32;
    const float* We = W + (size_t)e * K * N;
    unsigned short* Wte = Wt + (size_t)e * Np * Kp;
    int tx = threadIdx.x, ty = threadIdx.y;
#pragma unroll
    for (int j = 0; j < 8; ++j) {
        int k = kb + ty + j * 8, n = nb + tx;
        t[ty + j * 8][tx] = (k < K && n < N) ? We[(size_t)k * N + n] : 0.f;
    }
    __syncthreads();
#pragma unroll
    for (int j = 0; j < 4; ++j) {
        int n = ty + j * 8;
        unsigned int lo = f2bf(t[2 * tx][n]);
        unsigned int hi = f2bf(t[2 * tx + 1][n]);
        *(unsigned int*)&Wte[(size_t)(nb + n) * Kp + kb + 2 * tx] = lo | (hi << 16);
    }
}

// ---------------- GEMM: C[M,N] = A[M,K] @ Wt^T, routed m-tiles ----------------
// TM x TN tile, BK=64, WAVES waves each a 64x64 sub-tile (4x4 frags of 16x16x32).
// Single-barrier double-buffered pipeline. LDS XOR-swizzle (c ^ (r&7)). K%128==0.
// T1: bijective XCD-chunked block swizzle (m204) so consecutive y-tiles share an XCD L2.
template <int TM, int TN, int WAVES, bool FINAL, bool TAIL, bool SKIPLAST>
__global__ __launch_bounds__(WAVES * 64) void k_gemm(
    const unsigned short* __restrict__ A, int lda,
    const unsigned short* __restrict__ Bt, int K, int Np,
    const float* __restrict__ bias, int nvalid,
    unsigned short* __restrict__ C, int ldc,
    const int* __restrict__ hdr,
    const float* __restrict__ nextv, const int* __restrict__ row_of,
    float* __restrict__ accum)
{
    __shared__ unsigned short As[2][TM * 64];
    __shared__ unsigned short Bs[2][TN * 64];
    __shared__ float red[WAVES];

    constexpr int WGN = TN / 64;
    constexpr int LA  = TM / (WAVES * 8);
    constexpr int LB  = TN / (WAVES * 8);

    // ---- bijective XCD-chunked swizzle (T1) ----
    unsigned nwg  = gridDim.x * gridDim.y;
    unsigned orig = blockIdx.y * gridDim.x + blockIdx.x;
    unsigned q = nwg >> 3, r8 = nwg & 7, xcd = orig & 7, idx = orig >> 3;
    unsigned lin = (xcd < r8 ? xcd * (q + 1) : r8 * (q + 1) + (xcd - r8) * q) + idx;
    int bx = lin % gridDim.x, by = lin / gridDim.x;

    int mt128;
    if constexpr (TAIL) {
        mt128 = hdr[13] * 2 + by;            // the two 128-halves of the last 256-tile
    } else {
        if (SKIPLAST && by >= hdr[13] && TM == 256) return;
        mt128 = by * (TM / 128);
    }
    int e = hdr[32 + mt128];
    if (e < 0) return;
    int row0 = mt128 * 128;
    int n0   = bx * TN;

    int tid  = threadIdx.x;
    int wid  = tid >> 6, lane = tid & 63;
    int quad = lane >> 4, l15 = lane & 15;
    int sw   = l15 & 7;
    int wm = (wid / WGN) * 64, wn = (wid % WGN) * 64;

    const unsigned short* Ag = A  + (size_t)row0 * lda;
    const unsigned short* Bg = Bt + (size_t)e * Np * K + (size_t)n0 * K;
    const float* be = bias + (size_t)e * nvalid;

    int srow = lane >> 3;
    int scol = ((lane & 7) ^ srow) * 8;

    f32x4 acc[4][4];
#pragma unroll
    for (int i = 0; i < 4; ++i)
#pragma unroll
        for (int j = 0; j < 4; ++j)
            acc[i][j] = (f32x4){0.f, 0.f, 0.f, 0.f};

#define STAGE(K0, P)                                                              \
    {                                                                             \
        _Pragma("unroll")                                                         \
        for (int ii = 0; ii < LA; ++ii) {                                         \
            int rbase = wid * (TM / WAVES) + ii * 8;                              \
            const unsigned short* gp = Ag + (size_t)(rbase + srow) * lda + (K0) + scol; \
            __builtin_amdgcn_global_load_lds(                                     \
                (const __attribute__((address_space(1))) void*)gp,                \
                (__attribute__((address_space(3))) void*)(As[P] + rbase * 64), 16, 0, 0); \
        }                                                                         \
        _Pragma("unroll")                                                         \
        for (int ii = 0; ii < LB; ++ii) {                                         \
            int rbase = wid * (TN / WAVES) + ii * 8;                              \
            const unsigned short* gp = Bg + (size_t)(rbase + srow) * K + (K0) + scol;   \
            __builtin_amdgcn_global_load_lds(                                     \
                (const __attribute__((address_space(1))) void*)gp,                \
                (__attribute__((address_space(3))) void*)(Bs[P] + rbase * 64), 16, 0, 0); \
        }                                                                         \
    }

#define COMPUTE(P)                                                                \
    {                                                                             \
        _Pragma("unroll")                                                         \
        for (int kh = 0; kh < 2; ++kh) {                                          \
            bf16x8 af[4], bfr[4];                                                 \
            _Pragma("unroll")                                                     \
            for (int f = 0; f < 4; ++f) {                                         \
                int row = wm + f * 16 + l15;                                      \
                af[f] = *(const bf16x8*)(As[P] + row * 64 + (((kh * 4 + quad) ^ sw) << 3)); \
            }                                                                     \
            _Pragma("unroll")                                                     \
            for (int f = 0; f < 4; ++f) {                                         \
                int row = wn + f * 16 + l15;                                      \
                bfr[f] = *(const bf16x8*)(Bs[P] + row * 64 + (((kh * 4 + quad) ^ sw) << 3)); \
            }                                                                     \
            _Pragma("unroll")                                                     \
            for (int fm = 0; fm < 4; ++fm)                                        \
                _Pragma("unroll")                                                 \
                for (int fn = 0; fn < 4; ++fn)                                    \
                    acc[fm][fn] = __builtin_amdgcn_mfma_f32_16x16x32_bf16(        \
                        af[fm], bfr[fn], acc[fm][fn], 0, 0, 0);                   \
        }                                                                         \
    }

    STAGE(0, 0);
    __syncthreads();
    for (int k0 = 0; k0 < K; k0 += 128) {
        if (k0 + 64 < K) STAGE(k0 + 64, 1);
        COMPUTE(0);
        __syncthreads();
        if (k0 + 128 < K) STAGE(k0 + 128, 0);
        COMPUTE(1);
        __syncthreads();
    }
#undef STAGE
#undef COMPUTE

    if constexpr (!FINAL) {
#pragma unroll
        for (int fn = 0; fn < 4; ++fn) {
            int n = n0 + wn + fn * 16 + l15;
            float bv = be[n];
#pragma unroll
            for (int fm = 0; fm < 4; ++fm) {
#pragma unroll
                for (int i = 0; i < 4; ++i) {
                    int r = row0 + wm + fm * 16 + quad * 4 + i;
                    float v = acc[fm][fn][i] + bv;
                    v = v > 0.f ? v : 0.f;
                    C[(size_t)r * ldc + n] = f2bf(v);
                }
            }
        }
    } else {
        float local = 0.f;
#pragma unroll
        for (int fm = 0; fm < 4; ++fm) {
#pragma unroll
            for (int i = 0; i < 4; ++i) {
                int r = row0 + wm + fm * 16 + quad * 4 + i;
                int orig_r = row_of[r];
                if (orig_r >= 0) {
                    const float* nrow = nextv + (size_t)orig_r * XD;
#pragma unroll
                    for (int fn = 0; fn < 4; ++fn) {
                        int n = n0 + wn + fn * 16 + l15;
                        if (n < XD) {
                            float v = acc[fm][fn][i] + be[n];
                            float d = v - nrow[n];
                            local += d * d;
                        }
                    }
                }
            }
        }
        for (int off = 32; off > 0; off >>= 1)
            local += __shfl_down(local, off, 64);
        if (lane == 0) red[wid] = local;
        __syncthreads();
        if (tid == 0) {
            float s = 0.f;
#pragma unroll
            for (int w = 0; w < WAVES; ++w) s += red[w];
            atomicAdd(accum, s);
        }
    }
}

__global__ void k_final(const int* hdr, float* out) {
    if (blockIdx.x == 0 && threadIdx.x == 0) {
        float s = ((const float*)hdr)[16];
        out[0] = s / (float)(B_SZ * XD);
    }
}

// ---------------- host launch ----------------
extern "C" void kernel_launch(void* const* d_in, const int* in_sizes, int n_in,
                              void* d_out, int out_size, void* d_ws, size_t ws_size,
                              hipStream_t stream) {
    const float* x     = (const float*)d_in[0];
    const float* nextv = (const float*)d_in[1];
    const int*   a     = (const int*)d_in[2];
    const float* W0 = (const float*)d_in[3],  *b0 = (const float*)d_in[4];
    const float* W1 = (const float*)d_in[5],  *b1 = (const float*)d_in[6];
    const float* W2 = (const float*)d_in[7],  *b2 = (const float*)d_in[8];
    const float* W3 = (const float*)d_in[9],  *b3 = (const float*)d_in[10];
    const float* W4 = (const float*)d_in[11], *b4 = (const float*)d_in[12];

    int* hdr    = (int*)d_ws;                 // 128 ints
    int* row_of = hdr + 128;                  // MP ints
    unsigned short* xg = (unsigned short*)(row_of + MP);     // MP*384
    unsigned short* hA = xg + (size_t)MP * 384;              // MP*2048
    unsigned short* hB = hA + (size_t)MP * 2048;             // MP*2048
    unsigned short* Wt = hB + (size_t)MP * 2048;             // 3*2048*2048
    float* accum = (float*)(hdr + 16);

    k_route <<<1, 1024, 0, stream>>>(a, hdr, row_of);
    k_gather<<<MP, 384, 0, stream>>>(x, row_of, xg);

    // L0: (Mp,384) @ (384,1024)  -- 128x128 tiles (small K; fine-grained grid)
    k_transpose<<<dim3(6, 32, 3), dim3(32, 8), 0, stream>>>(W0, Wt, XD, 1024, 384, 1024);
    k_gemm<128, 128, 4, false, false, false><<<dim3(8, NTILES), 256, 0, stream>>>(
        xg, 384, Wt, 384, 1024, b0, 1024, hA, 1024, hdr, nullptr, nullptr, nullptr);

    // L1: (Mp,1024) @ (1024,2048) -- main 256x256x16 (typ. exactly 256 blocks) + 128x256x8 tail
    k_transpose<<<dim3(16, 64, 3), dim3(32, 8), 0, stream>>>(W1, Wt, 1024, 2048, 1024, 2048);
    k_gemm<256, 256, 16, false, false, true><<<dim3(8, NTILES / 2), 1024, 0, stream>>>(
        hA, 1024, Wt, 1024, 2048, b1, 2048, hB, 2048, hdr, nullptr, nullptr, nullptr);
    k_gemm<128, 256, 8, false, true, false><<<dim3(8, 2), 512, 0, stream>>>(
        hA, 1024, Wt, 1024, 2048, b1, 2048, hB, 2048, hdr, nullptr, nullptr, nullptr);

    // L2: (Mp,2048) @ (2048,2048) -- main + wide tail
    k_transpose<<<dim3(32, 64, 3), dim3(32, 8), 0, stream>>>(W2, Wt, 2048, 2048, 2048, 2048);
    k_gemm<256, 256, 16, false, false, true><<<dim3(8, NTILES / 2), 1024, 0, stream>>>(
        hB, 2048, Wt, 2048, 2048, b2, 2048, hA, 2048, hdr, nullptr, nullptr, nullptr);
    k_gemm<128, 256, 8, false, true, false><<<dim3(8, 2), 512, 0, stream>>>(
        hB, 2048, Wt, 2048, 2048, b2, 2048, hA, 2048, hdr, nullptr, nullptr, nullptr);

    // L3: (Mp,2048) @ (2048,1024) -- 128x256 x 8-wave, grid (4,70): full machine, no tail
    k_transpose<<<dim3(32, 32, 3), dim3(32, 8), 0, stream>>>(W3, Wt, 2048, 1024, 2048, 1024);
    k_gemm<128, 256, 8, false, false, false><<<dim3(4, NTILES), 512, 0, stream>>>(
        hA, 2048, Wt, 2048, 1024, b3, 1024, hB, 1024, hdr, nullptr, nullptr, nullptr);

    // L4: (Mp,1024) @ (1024,362->384), fused MSE -- all 128-tiles
    k_transpose<<<dim3(16, 12, 3), dim3(32, 8), 0, stream>>>(W4, Wt, 1024, XD, 1024, 384);
    k_gemm<128, 128, 4, true, false, false><<<dim3(3, NTILES), 256, 0, stream>>>(
        hB, 1024, Wt, 1024, 384, b4, XD, nullptr, 0, hdr, nextv, row_of, accum);

    k_final<<<1, 64, 0, stream>>>(hdr, (float*)d_out);
}

// Round 4
// 505.267 us; speedup vs baseline: 1.1477x; 1.1477x over previous
//
#include <hip/hip_runtime.h>
#include <hip/hip_bf16.h>

// ---------------- problem constants ----------------
#define B_SZ   8192
#define XD     362
#define NEXP   3
#define NTILES 70          // 128-row tile capacity (segments 256-aligned)
#define MP     (NTILES*128)

typedef __bf16 bf16x8 __attribute__((ext_vector_type(8)));
typedef float  f32x4  __attribute__((ext_vector_type(4)));

__device__ __forceinline__ unsigned short f2bf(float f) {
    unsigned u = __float_as_uint(f);
    u += 0x7fffu + ((u >> 16) & 1u);
    return (unsigned short)(u >> 16);
}

// hdr: [0..2]=counts, [6..8]=seg_start_row, [12]=total 128-tiles,
// [13]=last 256-tile index (nt/2-1), [16]=float accumulator,
// [32..101]=128-tile -> expert (-1 = inactive)
// Scan: wave-level __shfl_up inclusive scans (no barriers) + 1-thread wave-combine.
__global__ __launch_bounds__(1024) void k_route(const int* __restrict__ a,
                                                int* __restrict__ hdr,
                                                int* __restrict__ row_of) {
    __shared__ int wpre[3][16];
    __shared__ int stot[3];
    int tid = threadIdx.x, lane = tid & 63, w = tid >> 6;
    int ev[8];
    int c0 = 0, c1 = 0, c2 = 0;
#pragma unroll
    for (int j = 0; j < 8; ++j) {
        int e = a[tid * 8 + j];
        ev[j] = e;
        c0 += (e == 0); c1 += (e == 1); c2 += (e == 2);
    }
    int i0 = c0, i1 = c1, i2 = c2;           // inclusive wave scans
#pragma unroll
    for (int off = 1; off < 64; off <<= 1) {
        int t0_ = __shfl_up(i0, off, 64);
        int t1_ = __shfl_up(i1, off, 64);
        int t2_ = __shfl_up(i2, off, 64);
        if (lane >= off) { i0 += t0_; i1 += t1_; i2 += t2_; }
    }
    if (lane == 63) { wpre[0][w] = i0; wpre[1][w] = i1; wpre[2][w] = i2; }
    __syncthreads();
    if (tid == 0) {
        int s0 = 0, s1 = 0, s2 = 0;
#pragma unroll
        for (int k = 0; k < 16; ++k) {
            int a0 = wpre[0][k], a1 = wpre[1][k], a2 = wpre[2][k];
            wpre[0][k] = s0; wpre[1][k] = s1; wpre[2][k] = s2;
            s0 += a0; s1 += a1; s2 += a2;
        }
        stot[0] = s0; stot[1] = s1; stot[2] = s2;
    }
    __syncthreads();
    int tot0 = stot[0], tot1 = stot[1], tot2 = stot[2];
    int t0 = ((tot0 + 255) >> 8) << 1;   // 128-tiles per expert, 256-aligned
    int t1 = ((tot1 + 255) >> 8) << 1;
    int t2 = ((tot2 + 255) >> 8) << 1;
    int seg0 = 0, seg1 = t0 * 128, seg2 = (t0 + t1) * 128;
    int nt = t0 + t1 + t2;
    int b0 = seg0 + wpre[0][w] + i0 - c0;    // exclusive prefix
    int b1 = seg1 + wpre[1][w] + i1 - c1;
    int b2 = seg2 + wpre[2][w] + i2 - c2;
#pragma unroll
    for (int j = 0; j < 8; ++j) {
        int e = ev[j];
        int pos = (e == 0) ? b0++ : (e == 1) ? b1++ : b2++;
        row_of[pos] = tid * 8 + j;
    }
    if (tid == 0) {
        hdr[0] = tot0; hdr[1] = tot1; hdr[2] = tot2;
        hdr[6] = seg0; hdr[7] = seg1; hdr[8] = seg2;
        hdr[12] = nt;
        hdr[13] = nt / 2 - 1;     // last 256-row tile index
        hdr[16] = 0;
    }
    if (tid < NTILES)
        hdr[32 + tid] = (tid < t0) ? 0 : (tid < t0 + t1) ? 1 : (tid < nt) ? 2 : -1;
    for (int r = tid; r < MP; r += 1024) {
        int pad;
        if (r < seg1)           pad = (r - seg0) >= tot0;
        else if (r < seg2)      pad = (r - seg1) >= tot1;
        else if (r < nt * 128)  pad = (r - seg2) >= tot2;
        else                    pad = 1;
        if (pad) row_of[r] = -1;
    }
}

__global__ void k_gather(const float* __restrict__ x, const int* __restrict__ row_of,
                         unsigned short* __restrict__ xg) {
    int r = blockIdx.x;
    int c = threadIdx.x;
    int orig = row_of[r];
    float v = (orig >= 0 && c < XD) ? x[(size_t)orig * XD + c] : 0.f;
    xg[(size_t)r * 384 + c] = f2bf(v);
}

// ---------------- weight transpose+convert: W[e](K,N) f32 -> Wt[e](Np,Kp) bf16 ----------------
__device__ __forceinline__ void transpose_tile(const float* __restrict__ We,
                                               unsigned short* __restrict__ Wte,
                                               int K, int N, int Kp,
                                               int kb, int nb, int tx, int ty,
                                               float (*t)[33]) {
#pragma unroll
    for (int j = 0; j < 8; ++j) {
        int k = kb + ty + j * 8, n = nb + tx;
        t[ty + j * 8][tx] = (k < K && n < N) ? We[(size_t)k * N + n] : 0.f;
    }
    __syncthreads();
#pragma unroll
    for (int j = 0; j < 4; ++j) {
        int n = ty + j * 8;
        unsigned int lo = f2bf(t[2 * tx][n]);
        unsigned int hi = f2bf(t[2 * tx + 1][n]);
        *(unsigned int*)&Wte[(size_t)(nb + n) * Kp + kb + 2 * tx] = lo | (hi << 16);
    }
}

__global__ void k_transpose(const float* __restrict__ W, unsigned short* __restrict__ Wt,
                            int K, int N, int Kp, int Np) {
    __shared__ float t[64][33];
    int e  = blockIdx.z;
    int kb = blockIdx.x * 64, nb = blockIdx.y * 32;
    transpose_tile(W + (size_t)e * K * N, Wt + (size_t)e * Np * Kp,
                   K, N, Kp, kb, nb, threadIdx.x, threadIdx.y, t);
}

// all 5 layers x 3 experts in one dispatch. Per-layer tile counts (64k x 32n):
// L0: 6x32=192, L1: 16x64=1024, L2: 32x64=2048, L3: 32x32=1024, L4: 16x12=192 -> 4480
#define WT_OFF0 0
#define WT_OFF1 1179648u           // + 3*1024*384
#define WT_OFF2 7471104u           // + 3*2048*1024
#define WT_OFF3 20054016u          // + 3*2048*2048
#define WT_OFF4 26345472u          // + 3*1024*2048
#define WT_TOTAL 27525120u         // + 3*384*1024

__global__ void k_transpose_all(const float* __restrict__ W0, const float* __restrict__ W1,
                                const float* __restrict__ W2, const float* __restrict__ W3,
                                const float* __restrict__ W4, unsigned short* __restrict__ Wt) {
    __shared__ float t[64][33];
    int ti = blockIdx.x, e = blockIdx.z;
    const float* W; int K, N, Kp, kt; unsigned off; int Np;
    if (ti < 192)       { W = W0; K = 362;  N = 1024; Kp = 384;  Np = 1024; kt = 6;  off = WT_OFF0; }
    else if (ti < 1216) { W = W1; K = 1024; N = 2048; Kp = 1024; Np = 2048; kt = 16; off = WT_OFF1; ti -= 192; }
    else if (ti < 3264) { W = W2; K = 2048; N = 2048; Kp = 2048; Np = 2048; kt = 32; off = WT_OFF2; ti -= 1216; }
    else if (ti < 4288) { W = W3; K = 2048; N = 1024; Kp = 2048; Np = 1024; kt = 32; off = WT_OFF3; ti -= 3264; }
    else                { W = W4; K = 1024; N = 362;  Kp = 1024; Np = 384;  kt = 16; off = WT_OFF4; ti -= 4288; }
    int kb = (ti % kt) * 64, nb = (ti / kt) * 32;
    transpose_tile(W + (size_t)e * K * N, Wt + off + (size_t)e * Np * Kp,
                   K, N, Kp, kb, nb, threadIdx.x, threadIdx.y, t);
}

// ---------------- GEMM: C[M,N] = A[M,K] @ Wt^T, routed m-tiles ----------------
// TM x TN tile, BK=64, WAVES waves each a 64x64 sub-tile (4x4 frags of 16x16x32).
// Single-barrier double-buffered pipeline. LDS XOR-swizzle (c ^ (r&7)). K%128==0.
// NOTE: default x-fastest block mapping keeps each n-strip's B-panel L2-resident per
// XCD (gridDim.x==8) -> staged B loads are L2 hits. Do NOT XCD-swizzle (round-2: +53%).
template <int TM, int TN, int WAVES, bool FINAL, bool TAIL, bool SKIPLAST>
__global__ __launch_bounds__(WAVES * 64) void k_gemm(
    const unsigned short* __restrict__ A, int lda,
    const unsigned short* __restrict__ Bt, int K, int Np,
    const float* __restrict__ bias, int nvalid,
    unsigned short* __restrict__ C, int ldc,
    const int* __restrict__ hdr,
    const float* __restrict__ nextv, const int* __restrict__ row_of,
    float* __restrict__ accum)
{
    __shared__ unsigned short As[2][TM * 64];
    __shared__ unsigned short Bs[2][TN * 64];
    __shared__ float red[WAVES];

    constexpr int WGN = TN / 64;
    constexpr int LA  = TM / (WAVES * 8);
    constexpr int LB  = TN / (WAVES * 8);

    int mt128;
    if constexpr (TAIL) {
        mt128 = hdr[13] * 2 + blockIdx.y;    // the two 128-halves of the last 256-tile
    } else {
        if (SKIPLAST && (int)blockIdx.y >= hdr[13] && TM == 256) return;
        mt128 = blockIdx.y * (TM / 128);
    }
    int e = hdr[32 + mt128];
    if (e < 0) return;
    int row0 = mt128 * 128;
    int n0   = blockIdx.x * TN;

    int tid  = threadIdx.x;
    int wid  = tid >> 6, lane = tid & 63;
    int quad = lane >> 4, l15 = lane & 15;
    int sw   = l15 & 7;
    int wm = (wid / WGN) * 64, wn = (wid % WGN) * 64;

    const unsigned short* Ag = A  + (size_t)row0 * lda;
    const unsigned short* Bg = Bt + (size_t)e * Np * K + (size_t)n0 * K;
    const float* be = bias + (size_t)e * nvalid;

    int srow = lane >> 3;
    int scol = ((lane & 7) ^ srow) * 8;

    f32x4 acc[4][4];
#pragma unroll
    for (int i = 0; i < 4; ++i)
#pragma unroll
        for (int j = 0; j < 4; ++j)
            acc[i][j] = (f32x4){0.f, 0.f, 0.f, 0.f};

#define STAGE(K0, P)                                                              \
    {                                                                             \
        _Pragma("unroll")                                                         \
        for (int ii = 0; ii < LA; ++ii) {                                         \
            int rbase = wid * (TM / WAVES) + ii * 8;                              \
            const unsigned short* gp = Ag + (size_t)(rbase + srow) * lda + (K0) + scol; \
            __builtin_amdgcn_global_load_lds(                                     \
                (const __attribute__((address_space(1))) void*)gp,                \
                (__attribute__((address_space(3))) void*)(As[P] + rbase * 64), 16, 0, 0); \
        }                                                                         \
        _Pragma("unroll")                                                         \
        for (int ii = 0; ii < LB; ++ii) {                                         \
            int rbase = wid * (TN / WAVES) + ii * 8;                              \
            const unsigned short* gp = Bg + (size_t)(rbase + srow) * K + (K0) + scol;   \
            __builtin_amdgcn_global_load_lds(                                     \
                (const __attribute__((address_space(1))) void*)gp,                \
                (__attribute__((address_space(3))) void*)(Bs[P] + rbase * 64), 16, 0, 0); \
        }                                                                         \
    }

#define COMPUTE(P)                                                                \
    {                                                                             \
        _Pragma("unroll")                                                         \
        for (int kh = 0; kh < 2; ++kh) {                                          \
            bf16x8 af[4], bfr[4];                                                 \
            _Pragma("unroll")                                                     \
            for (int f = 0; f < 4; ++f) {                                         \
                int row = wm + f * 16 + l15;                                      \
                af[f] = *(const bf16x8*)(As[P] + row * 64 + (((kh * 4 + quad) ^ sw) << 3)); \
            }                                                                     \
            _Pragma("unroll")                                                     \
            for (int f = 0; f < 4; ++f) {                                         \
                int row = wn + f * 16 + l15;                                      \
                bfr[f] = *(const bf16x8*)(Bs[P] + row * 64 + (((kh * 4 + quad) ^ sw) << 3)); \
            }                                                                     \
            _Pragma("unroll")                                                     \
            for (int fm = 0; fm < 4; ++fm)                                        \
                _Pragma("unroll")                                                 \
                for (int fn = 0; fn < 4; ++fn)                                    \
                    acc[fm][fn] = __builtin_amdgcn_mfma_f32_16x16x32_bf16(        \
                        af[fm], bfr[fn], acc[fm][fn], 0, 0, 0);                   \
        }                                                                         \
    }

    STAGE(0, 0);
    __syncthreads();
    for (int k0 = 0; k0 < K; k0 += 128) {
        if (k0 + 64 < K) STAGE(k0 + 64, 1);
        COMPUTE(0);
        __syncthreads();
        if (k0 + 128 < K) STAGE(k0 + 128, 0);
        COMPUTE(1);
        __syncthreads();
    }
#undef STAGE
#undef COMPUTE

    if constexpr (!FINAL) {
#pragma unroll
        for (int fn = 0; fn < 4; ++fn) {
            int n = n0 + wn + fn * 16 + l15;
            float bv = be[n];
#pragma unroll
            for (int fm = 0; fm < 4; ++fm) {
#pragma unroll
                for (int i = 0; i < 4; ++i) {
                    int r = row0 + wm + fm * 16 + quad * 4 + i;
                    float v = acc[fm][fn][i] + bv;
                    v = v > 0.f ? v : 0.f;
                    C[(size_t)r * ldc + n] = f2bf(v);
                }
            }
        }
    } else {
        float local = 0.f;
#pragma unroll
        for (int fm = 0; fm < 4; ++fm) {
#pragma unroll
            for (int i = 0; i < 4; ++i) {
                int r = row0 + wm + fm * 16 + quad * 4 + i;
                int orig_r = row_of[r];
                if (orig_r >= 0) {
                    const float* nrow = nextv + (size_t)orig_r * XD;
#pragma unroll
                    for (int fn = 0; fn < 4; ++fn) {
                        int n = n0 + wn + fn * 16 + l15;
                        if (n < XD) {
                            float v = acc[fm][fn][i] + be[n];
                            float d = v - nrow[n];
                            local += d * d;
                        }
                    }
                }
            }
        }
        for (int off = 32; off > 0; off >>= 1)
            local += __shfl_down(local, off, 64);
        if (lane == 0) red[wid] = local;
        __syncthreads();
        if (tid == 0) {
            float s = 0.f;
#pragma unroll
            for (int w = 0; w < WAVES; ++w) s += red[w];
            atomicAdd(accum, s);
        }
    }
}

__global__ void k_final(const int* hdr, float* out) {
    if (blockIdx.x == 0 && threadIdx.x == 0) {
        float s = ((const float*)hdr)[16];
        out[0] = s / (float)(B_SZ * XD);
    }
}

// ---------------- host launch ----------------
extern "C" void kernel_launch(void* const* d_in, const int* in_sizes, int n_in,
                              void* d_out, int out_size, void* d_ws, size_t ws_size,
                              hipStream_t stream) {
    const float* x     = (const float*)d_in[0];
    const float* nextv = (const float*)d_in[1];
    const int*   a     = (const int*)d_in[2];
    const float* W0 = (const float*)d_in[3],  *b0 = (const float*)d_in[4];
    const float* W1 = (const float*)d_in[5],  *b1 = (const float*)d_in[6];
    const float* W2 = (const float*)d_in[7],  *b2 = (const float*)d_in[8];
    const float* W3 = (const float*)d_in[9],  *b3 = (const float*)d_in[10];
    const float* W4 = (const float*)d_in[11], *b4 = (const float*)d_in[12];

    int* hdr    = (int*)d_ws;                 // 128 ints
    int* row_of = hdr + 128;                  // MP ints
    unsigned short* xg = (unsigned short*)(row_of + MP);     // MP*384
    unsigned short* hA = xg + (size_t)MP * 384;              // MP*2048
    unsigned short* hB = hA + (size_t)MP * 2048;             // MP*2048
    unsigned short* Wt = hB + (size_t)MP * 2048;             // merged: 55MB; serial: 24MB
    float* accum = (float*)(hdr + 16);

    size_t base = (size_t)(128 + MP) * 4 + (size_t)MP * 384 * 2 + (size_t)MP * 2048 * 2 * 2;
    bool merged = ws_size >= base + (size_t)WT_TOTAL * 2;

    unsigned short *Wt0, *Wt1, *Wt2, *Wt3, *Wt4;
    if (merged) {
        Wt0 = Wt + WT_OFF0; Wt1 = Wt + WT_OFF1; Wt2 = Wt + WT_OFF2;
        Wt3 = Wt + WT_OFF3; Wt4 = Wt + WT_OFF4;
        k_transpose_all<<<dim3(4480, 1, 3), dim3(32, 8), 0, stream>>>(W0, W1, W2, W3, W4, Wt);
    } else {
        Wt0 = Wt1 = Wt2 = Wt3 = Wt4 = Wt;
    }

    k_route <<<1, 1024, 0, stream>>>(a, hdr, row_of);
    k_gather<<<MP, 384, 0, stream>>>(x, row_of, xg);

    // L0: (Mp,384) @ (384,1024)  -- 128x128 tiles (small K; fine-grained grid)
    if (!merged) k_transpose<<<dim3(6, 32, 3), dim3(32, 8), 0, stream>>>(W0, Wt0, XD, 1024, 384, 1024);
    k_gemm<128, 128, 4, false, false, false><<<dim3(8, NTILES), 256, 0, stream>>>(
        xg, 384, Wt0, 384, 1024, b0, 1024, hA, 1024, hdr, nullptr, nullptr, nullptr);

    // L1: (Mp,1024) @ (1024,2048) -- main 256x256x16 (typ. exactly 256 blocks) + 128x256x8 tail
    if (!merged) k_transpose<<<dim3(16, 64, 3), dim3(32, 8), 0, stream>>>(W1, Wt1, 1024, 2048, 1024, 2048);
    k_gemm<256, 256, 16, false, false, true><<<dim3(8, NTILES / 2), 1024, 0, stream>>>(
        hA, 1024, Wt1, 1024, 2048, b1, 2048, hB, 2048, hdr, nullptr, nullptr, nullptr);
    k_gemm<128, 256, 8, false, true, false><<<dim3(8, 2), 512, 0, stream>>>(
        hA, 1024, Wt1, 1024, 2048, b1, 2048, hB, 2048, hdr, nullptr, nullptr, nullptr);

    // L2: (Mp,2048) @ (2048,2048) -- main + wide tail
    if (!merged) k_transpose<<<dim3(32, 64, 3), dim3(32, 8), 0, stream>>>(W2, Wt2, 2048, 2048, 2048, 2048);
    k_gemm<256, 256, 16, false, false, true><<<dim3(8, NTILES / 2), 1024, 0, stream>>>(
        hB, 2048, Wt2, 2048, 2048, b2, 2048, hA, 2048, hdr, nullptr, nullptr, nullptr);
    k_gemm<128, 256, 8, false, true, false><<<dim3(8, 2), 512, 0, stream>>>(
        hB, 2048, Wt2, 2048, 2048, b2, 2048, hA, 2048, hdr, nullptr, nullptr, nullptr);

    // L3: (Mp,2048) @ (2048,1024) -- 128x128x4: 64KB LDS -> 2 blocks/CU co-resident, no tail
    if (!merged) k_transpose<<<dim3(32, 32, 3), dim3(32, 8), 0, stream>>>(W3, Wt3, 2048, 1024, 2048, 1024);
    k_gemm<128, 128, 4, false, false, false><<<dim3(8, NTILES), 256, 0, stream>>>(
        hA, 2048, Wt3, 2048, 1024, b3, 1024, hB, 1024, hdr, nullptr, nullptr, nullptr);

    // L4: (Mp,1024) @ (1024,362->384), fused MSE -- all 128-tiles
    if (!merged) k_transpose<<<dim3(16, 12, 3), dim3(32, 8), 0, stream>>>(W4, Wt4, 1024, XD, 1024, 384);
    k_gemm<128, 128, 4, true, false, false><<<dim3(3, NTILES), 256, 0, stream>>>(
        hB, 1024, Wt4, 1024, 384, b4, XD, nullptr, 0, hdr, nextv, row_of, accum);

    k_final<<<1, 64, 0, stream>>>(hdr, (float*)d_out);
}

// Round 5
// 487.461 us; speedup vs baseline: 1.1896x; 1.0365x over previous
//
#include <hip/hip_runtime.h>
#include <hip/hip_bf16.h>

// ---------------- problem constants ----------------
#define B_SZ   8192
#define XD     362
#define NEXP   3
#define NTILES 70          // 128-row tile capacity (segments 256-aligned)
#define MP     (NTILES*128)

typedef __bf16 bf16x8 __attribute__((ext_vector_type(8)));
typedef float  f32x4  __attribute__((ext_vector_type(4)));

__device__ __forceinline__ unsigned short f2bf(float f) {
    unsigned u = __float_as_uint(f);
    u += 0x7fffu + ((u >> 16) & 1u);
    return (unsigned short)(u >> 16);
}

// hdr: [0..2]=counts, [6..8]=seg_start_row, [12]=total 128-tiles,
// [13]=last 256-tile index (nt/2-1), [16]=float accumulator,
// [32..101]=128-tile -> expert (-1 = inactive)
// Scan: wave-level __shfl_up inclusive scans (no barriers) + 1-thread wave-combine.
__global__ __launch_bounds__(1024) void k_route(const int* __restrict__ a,
                                                int* __restrict__ hdr,
                                                int* __restrict__ row_of) {
    __shared__ int wpre[3][16];
    __shared__ int stot[3];
    int tid = threadIdx.x, lane = tid & 63, w = tid >> 6;
    int ev[8];
    int c0 = 0, c1 = 0, c2 = 0;
#pragma unroll
    for (int j = 0; j < 8; ++j) {
        int e = a[tid * 8 + j];
        ev[j] = e;
        c0 += (e == 0); c1 += (e == 1); c2 += (e == 2);
    }
    int i0 = c0, i1 = c1, i2 = c2;           // inclusive wave scans
#pragma unroll
    for (int off = 1; off < 64; off <<= 1) {
        int t0_ = __shfl_up(i0, off, 64);
        int t1_ = __shfl_up(i1, off, 64);
        int t2_ = __shfl_up(i2, off, 64);
        if (lane >= off) { i0 += t0_; i1 += t1_; i2 += t2_; }
    }
    if (lane == 63) { wpre[0][w] = i0; wpre[1][w] = i1; wpre[2][w] = i2; }
    __syncthreads();
    if (tid == 0) {
        int s0 = 0, s1 = 0, s2 = 0;
#pragma unroll
        for (int k = 0; k < 16; ++k) {
            int a0 = wpre[0][k], a1 = wpre[1][k], a2 = wpre[2][k];
            wpre[0][k] = s0; wpre[1][k] = s1; wpre[2][k] = s2;
            s0 += a0; s1 += a1; s2 += a2;
        }
        stot[0] = s0; stot[1] = s1; stot[2] = s2;
    }
    __syncthreads();
    int tot0 = stot[0], tot1 = stot[1], tot2 = stot[2];
    int t0 = ((tot0 + 255) >> 8) << 1;   // 128-tiles per expert, 256-aligned
    int t1 = ((tot1 + 255) >> 8) << 1;
    int t2 = ((tot2 + 255) >> 8) << 1;
    int seg0 = 0, seg1 = t0 * 128, seg2 = (t0 + t1) * 128;
    int nt = t0 + t1 + t2;
    int b0 = seg0 + wpre[0][w] + i0 - c0;    // exclusive prefix
    int b1 = seg1 + wpre[1][w] + i1 - c1;
    int b2 = seg2 + wpre[2][w] + i2 - c2;
#pragma unroll
    for (int j = 0; j < 8; ++j) {
        int e = ev[j];
        int pos = (e == 0) ? b0++ : (e == 1) ? b1++ : b2++;
        row_of[pos] = tid * 8 + j;
    }
    if (tid == 0) {
        hdr[0] = tot0; hdr[1] = tot1; hdr[2] = tot2;
        hdr[6] = seg0; hdr[7] = seg1; hdr[8] = seg2;
        hdr[12] = nt;
        hdr[13] = nt / 2 - 1;     // last 256-row tile index
        hdr[16] = 0;
    }
    if (tid < NTILES)
        hdr[32 + tid] = (tid < t0) ? 0 : (tid < t0 + t1) ? 1 : (tid < nt) ? 2 : -1;
    for (int r = tid; r < MP; r += 1024) {
        int pad;
        if (r < seg1)           pad = (r - seg0) >= tot0;
        else if (r < seg2)      pad = (r - seg1) >= tot1;
        else if (r < nt * 128)  pad = (r - seg2) >= tot2;
        else                    pad = 1;
        if (pad) row_of[r] = -1;
    }
}

__global__ void k_gather(const float* __restrict__ x, const int* __restrict__ row_of,
                         unsigned short* __restrict__ xg) {
    int r = blockIdx.x;
    int c = threadIdx.x;
    int orig = row_of[r];
    float v = (orig >= 0 && c < XD) ? x[(size_t)orig * XD + c] : 0.f;
    xg[(size_t)r * 384 + c] = f2bf(v);
}

// ---------------- weight transpose+convert: W[e](K,N) f32 -> Wt[e](Np,Kp) bf16 ----------------
__device__ __forceinline__ void transpose_tile(const float* __restrict__ We,
                                               unsigned short* __restrict__ Wte,
                                               int K, int N, int Kp,
                                               int kb, int nb, int tx, int ty,
                                               float (*t)[33]) {
#pragma unroll
    for (int j = 0; j < 8; ++j) {
        int k = kb + ty + j * 8, n = nb + tx;
        t[ty + j * 8][tx] = (k < K && n < N) ? We[(size_t)k * N + n] : 0.f;
    }
    __syncthreads();
#pragma unroll
    for (int j = 0; j < 4; ++j) {
        int n = ty + j * 8;
        unsigned int lo = f2bf(t[2 * tx][n]);
        unsigned int hi = f2bf(t[2 * tx + 1][n]);
        *(unsigned int*)&Wte[(size_t)(nb + n) * Kp + kb + 2 * tx] = lo | (hi << 16);
    }
}

__global__ void k_transpose(const float* __restrict__ W, unsigned short* __restrict__ Wt,
                            int K, int N, int Kp, int Np) {
    __shared__ float t[64][33];
    int e  = blockIdx.z;
    int kb = blockIdx.x * 64, nb = blockIdx.y * 32;
    transpose_tile(W + (size_t)e * K * N, Wt + (size_t)e * Np * Kp,
                   K, N, Kp, kb, nb, threadIdx.x, threadIdx.y, t);
}

// all 5 layers x 3 experts in one dispatch. Per-layer tile counts (64k x 32n):
// L0: 6x32=192, L1: 16x64=1024, L2: 32x64=2048, L3: 32x32=1024, L4: 16x12=192 -> 4480
#define WT_OFF0 0
#define WT_OFF1 1179648u           // + 3*1024*384
#define WT_OFF2 7471104u           // + 3*2048*1024
#define WT_OFF3 20054016u          // + 3*2048*2048
#define WT_OFF4 26345472u          // + 3*1024*2048
#define WT_TOTAL 27525120u         // + 3*384*1024

__global__ void k_transpose_all(const float* __restrict__ W0, const float* __restrict__ W1,
                                const float* __restrict__ W2, const float* __restrict__ W3,
                                const float* __restrict__ W4, unsigned short* __restrict__ Wt) {
    __shared__ float t[64][33];
    int ti = blockIdx.x, e = blockIdx.z;
    const float* W; int K, N, Kp, kt; unsigned off; int Np;
    if (ti < 192)       { W = W0; K = 362;  N = 1024; Kp = 384;  Np = 1024; kt = 6;  off = WT_OFF0; }
    else if (ti < 1216) { W = W1; K = 1024; N = 2048; Kp = 1024; Np = 2048; kt = 16; off = WT_OFF1; ti -= 192; }
    else if (ti < 3264) { W = W2; K = 2048; N = 2048; Kp = 2048; Np = 2048; kt = 32; off = WT_OFF2; ti -= 1216; }
    else if (ti < 4288) { W = W3; K = 2048; N = 1024; Kp = 2048; Np = 1024; kt = 32; off = WT_OFF3; ti -= 3264; }
    else                { W = W4; K = 1024; N = 362;  Kp = 1024; Np = 384;  kt = 16; off = WT_OFF4; ti -= 4288; }
    int kb = (ti % kt) * 64, nb = (ti / kt) * 32;
    transpose_tile(W + (size_t)e * K * N, Wt + off + (size_t)e * Np * Kp,
                   K, N, Kp, kb, nb, threadIdx.x, threadIdx.y, t);
}

// ---------------- GEMM: C[M,N] = A[M,K] @ Wt^T, routed m-tiles ----------------
// TM x TN tile, BK=64, WAVES=(TM/64)*(TN/64) waves each a 64x64 sub-tile.
// Single-barrier double-buffered pipeline. LDS XOR-swizzle (c ^ (r&7)). K%128==0.
// Measured config ranking (r0/r4): 16-wave 256^2 block > 4-wave 128^2 for long K
// (per-block wave depth hides the barrier drain; grid width does not).
// Do NOT XCD-swizzle (round-2: +53% regression; kernel is latency-bound, default
// x-fastest mapping keeps the B panel L2-resident per XCD).
// KSPLIT>1 (tail path): blockIdx.z selects a K/KSPLIT chunk; f32 partials (no
// bias/relu) are written to 'accum' as P[z][256][Np]; k_tailc combines.
template <int TM, int TN, int WAVES, bool FINAL, bool TAIL, bool SKIPLAST, int KSPLIT = 1>
__global__ __launch_bounds__(WAVES * 64) void k_gemm(
    const unsigned short* __restrict__ A, int lda,
    const unsigned short* __restrict__ Bt, int K, int Np,
    const float* __restrict__ bias, int nvalid,
    unsigned short* __restrict__ C, int ldc,
    const int* __restrict__ hdr,
    const float* __restrict__ nextv, const int* __restrict__ row_of,
    float* __restrict__ accum)
{
    __shared__ unsigned short As[2][TM * 64];
    __shared__ unsigned short Bs[2][TN * 64];
    __shared__ float red[WAVES];

    constexpr int WGN = TN / 64;
    constexpr int LA  = TM / (WAVES * 8);
    constexpr int LB  = TN / (WAVES * 8);

    int mt128;
    if constexpr (TAIL) {
        mt128 = hdr[13] * 2 + blockIdx.y;    // the two 128-halves of the last 256-tile
    } else {
        if (SKIPLAST && (int)blockIdx.y >= hdr[13] && TM == 256) return;
        mt128 = blockIdx.y * (TM / 128);
    }
    int e = hdr[32 + mt128];
    if (e < 0) return;
    int row0 = mt128 * 128;
    int n0   = blockIdx.x * TN;

    int tid  = threadIdx.x;
    int wid  = tid >> 6, lane = tid & 63;
    int quad = lane >> 4, l15 = lane & 15;
    int sw   = l15 & 7;
    int wm = (wid / WGN) * 64, wn = (wid % WGN) * 64;

    const unsigned short* Ag = A  + (size_t)row0 * lda;
    const unsigned short* Bg = Bt + (size_t)e * Np * K + (size_t)n0 * K;
    const float* be = bias + (size_t)e * nvalid;

    int srow = lane >> 3;
    int scol = ((lane & 7) ^ srow) * 8;

    int kbeg = 0, kend = K;
    if constexpr (KSPLIT > 1) {
        int kh = K / KSPLIT;                 // multiple of 128 for all uses
        kbeg = blockIdx.z * kh;
        kend = kbeg + kh;
    }

    f32x4 acc[4][4];
#pragma unroll
    for (int i = 0; i < 4; ++i)
#pragma unroll
        for (int j = 0; j < 4; ++j)
            acc[i][j] = (f32x4){0.f, 0.f, 0.f, 0.f};

#define STAGE(K0, P)                                                              \
    {                                                                             \
        _Pragma("unroll")                                                         \
        for (int ii = 0; ii < LA; ++ii) {                                         \
            int rbase = wid * (TM / WAVES) + ii * 8;                              \
            const unsigned short* gp = Ag + (size_t)(rbase + srow) * lda + (K0) + scol; \
            __builtin_amdgcn_global_load_lds(                                     \
                (const __attribute__((address_space(1))) void*)gp,                \
                (__attribute__((address_space(3))) void*)(As[P] + rbase * 64), 16, 0, 0); \
        }                                                                         \
        _Pragma("unroll")                                                         \
        for (int ii = 0; ii < LB; ++ii) {                                         \
            int rbase = wid * (TN / WAVES) + ii * 8;                              \
            const unsigned short* gp = Bg + (size_t)(rbase + srow) * K + (K0) + scol;   \
            __builtin_amdgcn_global_load_lds(                                     \
                (const __attribute__((address_space(1))) void*)gp,                \
                (__attribute__((address_space(3))) void*)(Bs[P] + rbase * 64), 16, 0, 0); \
        }                                                                         \
    }

#define COMPUTE(P)                                                                \
    {                                                                             \
        _Pragma("unroll")                                                         \
        for (int kh2 = 0; kh2 < 2; ++kh2) {                                       \
            bf16x8 af[4], bfr[4];                                                 \
            _Pragma("unroll")                                                     \
            for (int f = 0; f < 4; ++f) {                                         \
                int row = wm + f * 16 + l15;                                      \
                af[f] = *(const bf16x8*)(As[P] + row * 64 + (((kh2 * 4 + quad) ^ sw) << 3)); \
            }                                                                     \
            _Pragma("unroll")                                                     \
            for (int f = 0; f < 4; ++f) {                                         \
                int row = wn + f * 16 + l15;                                      \
                bfr[f] = *(const bf16x8*)(Bs[P] + row * 64 + (((kh2 * 4 + quad) ^ sw) << 3)); \
            }                                                                     \
            _Pragma("unroll")                                                     \
            for (int fm = 0; fm < 4; ++fm)                                        \
                _Pragma("unroll")                                                 \
                for (int fn = 0; fn < 4; ++fn)                                    \
                    acc[fm][fn] = __builtin_amdgcn_mfma_f32_16x16x32_bf16(        \
                        af[fm], bfr[fn], acc[fm][fn], 0, 0, 0);                   \
        }                                                                         \
    }

    STAGE(kbeg, 0);
    __syncthreads();
    for (int k0 = kbeg; k0 < kend; k0 += 128) {
        if (k0 + 64 < kend) STAGE(k0 + 64, 1);
        COMPUTE(0);
        __syncthreads();
        if (k0 + 128 < kend) STAGE(k0 + 128, 0);
        COMPUTE(1);
        __syncthreads();
    }
#undef STAGE
#undef COMPUTE

    if constexpr (KSPLIT > 1) {
        // f32 partials, no bias/relu; P[z][256][Np]
        float* P = accum + (size_t)blockIdx.z * 256 * Np;
#pragma unroll
        for (int fn = 0; fn < 4; ++fn) {
            int n = n0 + wn + fn * 16 + l15;
#pragma unroll
            for (int fm = 0; fm < 4; ++fm) {
#pragma unroll
                for (int i = 0; i < 4; ++i) {
                    int rl = blockIdx.y * 128 + wm + fm * 16 + quad * 4 + i;
                    P[(size_t)rl * Np + n] = acc[fm][fn][i];
                }
            }
        }
    } else if constexpr (!FINAL) {
#pragma unroll
        for (int fn = 0; fn < 4; ++fn) {
            int n = n0 + wn + fn * 16 + l15;
            float bv = be[n];
#pragma unroll
            for (int fm = 0; fm < 4; ++fm) {
#pragma unroll
                for (int i = 0; i < 4; ++i) {
                    int r = row0 + wm + fm * 16 + quad * 4 + i;
                    float v = acc[fm][fn][i] + bv;
                    v = v > 0.f ? v : 0.f;
                    C[(size_t)r * ldc + n] = f2bf(v);
                }
            }
        }
    } else {
        float local = 0.f;
#pragma unroll
        for (int fm = 0; fm < 4; ++fm) {
#pragma unroll
            for (int i = 0; i < 4; ++i) {
                int r = row0 + wm + fm * 16 + quad * 4 + i;
                int orig_r = row_of[r];
                if (orig_r >= 0) {
                    const float* nrow = nextv + (size_t)orig_r * XD;
#pragma unroll
                    for (int fn = 0; fn < 4; ++fn) {
                        int n = n0 + wn + fn * 16 + l15;
                        if (n < XD) {
                            float v = acc[fm][fn][i] + be[n];
                            float d = v - nrow[n];
                            local += d * d;
                        }
                    }
                }
            }
        }
        for (int off = 32; off > 0; off >>= 1)
            local += __shfl_down(local, off, 64);
        if (lane == 0) red[wid] = local;
        __syncthreads();
        if (tid == 0) {
            float s = 0.f;
#pragma unroll
            for (int w = 0; w < WAVES; ++w) s += red[w];
            atomicAdd(accum, s);
        }
    }
}

// combine split-K tail partials: C[row0+r][n] = bf16(relu(sum_z P[z][r][n] + bias))
__global__ void k_tailc(const float* __restrict__ P, const float* __restrict__ bias,
                        int Np, int KS, unsigned short* __restrict__ C, int ldc,
                        const int* __restrict__ hdr) {
    int r = blockIdx.x;                       // 0..255
    int e = hdr[32 + hdr[13] * 2];            // both halves share one expert (256-aligned)
    int row = hdr[13] * 256 + r;
    const float* be = bias + (size_t)e * Np;
    for (int n = threadIdx.x; n < Np; n += blockDim.x) {
        float s = 0.f;
        for (int z = 0; z < KS; ++z) s += P[((size_t)z * 256 + r) * Np + n];
        float v = s + be[n];
        v = v > 0.f ? v : 0.f;
        C[(size_t)row * ldc + n] = f2bf(v);
    }
}

__global__ void k_final(const int* hdr, float* out) {
    if (blockIdx.x == 0 && threadIdx.x == 0) {
        float s = ((const float*)hdr)[16];
        out[0] = s / (float)(B_SZ * XD);
    }
}

// ---------------- host launch ----------------
extern "C" void kernel_launch(void* const* d_in, const int* in_sizes, int n_in,
                              void* d_out, int out_size, void* d_ws, size_t ws_size,
                              hipStream_t stream) {
    const float* x     = (const float*)d_in[0];
    const float* nextv = (const float*)d_in[1];
    const int*   a     = (const int*)d_in[2];
    const float* W0 = (const float*)d_in[3],  *b0 = (const float*)d_in[4];
    const float* W1 = (const float*)d_in[5],  *b1 = (const float*)d_in[6];
    const float* W2 = (const float*)d_in[7],  *b2 = (const float*)d_in[8];
    const float* W3 = (const float*)d_in[9],  *b3 = (const float*)d_in[10];
    const float* W4 = (const float*)d_in[11], *b4 = (const float*)d_in[12];

    int* hdr    = (int*)d_ws;                 // 128 ints
    int* row_of = hdr + 128;                  // MP ints
    unsigned short* xg = (unsigned short*)(row_of + MP);     // MP*384
    unsigned short* hA = xg + (size_t)MP * 384;              // MP*2048
    unsigned short* hB = hA + (size_t)MP * 2048;             // MP*2048
    unsigned short* Wt = hB + (size_t)MP * 2048;             // merged: 55MB; serial: 24MB
    float* accum = (float*)(hdr + 16);

    size_t base = (size_t)(128 + MP) * 4 + (size_t)MP * 384 * 2 + (size_t)MP * 2048 * 2 * 2;
    const size_t PBYTES = (size_t)4 * 256 * 2048 * 4;        // KS=4 x 256 rows x 2048 f32
    bool merged = ws_size >= base + (size_t)WT_TOTAL * 2;
    float* Ppart = (float*)(Wt + WT_TOTAL);                  // after merged Wt region
    bool sk = merged && ws_size >= base + (size_t)WT_TOTAL * 2 + PBYTES;

    unsigned short *Wt0, *Wt1, *Wt2, *Wt3, *Wt4;
    if (merged) {
        Wt0 = Wt + WT_OFF0; Wt1 = Wt + WT_OFF1; Wt2 = Wt + WT_OFF2;
        Wt3 = Wt + WT_OFF3; Wt4 = Wt + WT_OFF4;
        k_transpose_all<<<dim3(4480, 1, 3), dim3(32, 8), 0, stream>>>(W0, W1, W2, W3, W4, Wt);
    } else {
        Wt0 = Wt1 = Wt2 = Wt3 = Wt4 = Wt;
    }

    k_route <<<1, 1024, 0, stream>>>(a, hdr, row_of);
    k_gather<<<MP, 384, 0, stream>>>(x, row_of, xg);

    // L0: (Mp,384) @ (384,1024)  -- 128x128 tiles (small K; fine-grained grid)
    if (!merged) k_transpose<<<dim3(6, 32, 3), dim3(32, 8), 0, stream>>>(W0, Wt0, XD, 1024, 384, 1024);
    k_gemm<128, 128, 4, false, false, false><<<dim3(8, NTILES), 256, 0, stream>>>(
        xg, 384, Wt0, 384, 1024, b0, 1024, hA, 1024, hdr, nullptr, nullptr, nullptr);

    // L1: (Mp,1024) @ (1024,2048) -- main 256x256x16 (exactly 256 blocks) + split-K tail
    if (!merged) k_transpose<<<dim3(16, 64, 3), dim3(32, 8), 0, stream>>>(W1, Wt1, 1024, 2048, 1024, 2048);
    k_gemm<256, 256, 16, false, false, true><<<dim3(8, NTILES / 2), 1024, 0, stream>>>(
        hA, 1024, Wt1, 1024, 2048, b1, 2048, hB, 2048, hdr, nullptr, nullptr, nullptr);
    if (sk) {
        k_gemm<128, 256, 8, false, true, false, 4><<<dim3(8, 2, 4), 512, 0, stream>>>(
            hA, 1024, Wt1, 1024, 2048, b1, 2048, hB, 2048, hdr, nullptr, nullptr, Ppart);
        k_tailc<<<256, 256, 0, stream>>>(Ppart, b1, 2048, 4, hB, 2048, hdr);
    } else {
        k_gemm<128, 256, 8, false, true, false><<<dim3(8, 2), 512, 0, stream>>>(
            hA, 1024, Wt1, 1024, 2048, b1, 2048, hB, 2048, hdr, nullptr, nullptr, nullptr);
    }

    // L2: (Mp,2048) @ (2048,2048) -- main + split-K tail
    if (!merged) k_transpose<<<dim3(32, 64, 3), dim3(32, 8), 0, stream>>>(W2, Wt2, 2048, 2048, 2048, 2048);
    k_gemm<256, 256, 16, false, false, true><<<dim3(8, NTILES / 2), 1024, 0, stream>>>(
        hB, 2048, Wt2, 2048, 2048, b2, 2048, hA, 2048, hdr, nullptr, nullptr, nullptr);
    if (sk) {
        k_gemm<128, 256, 8, false, true, false, 4><<<dim3(8, 2, 4), 512, 0, stream>>>(
            hB, 2048, Wt2, 2048, 2048, b2, 2048, hA, 2048, hdr, nullptr, nullptr, Ppart);
        k_tailc<<<256, 256, 0, stream>>>(Ppart, b2, 2048, 4, hA, 2048, hdr);
    } else {
        k_gemm<128, 256, 8, false, true, false><<<dim3(8, 2), 512, 0, stream>>>(
            hB, 2048, Wt2, 2048, 2048, b2, 2048, hA, 2048, hdr, nullptr, nullptr, nullptr);
    }

    // L3: (Mp,2048) @ (2048,1024) -- 256x256x16 main (measured best per-CU config) + split-K tail
    if (!merged) k_transpose<<<dim3(32, 32, 3), dim3(32, 8), 0, stream>>>(W3, Wt3, 2048, 1024, 2048, 1024);
    k_gemm<256, 256, 16, false, false, true><<<dim3(4, NTILES / 2), 1024, 0, stream>>>(
        hA, 2048, Wt3, 2048, 1024, b3, 1024, hB, 1024, hdr, nullptr, nullptr, nullptr);
    if (sk) {
        k_gemm<128, 256, 8, false, true, false, 4><<<dim3(4, 2, 4), 512, 0, stream>>>(
            hA, 2048, Wt3, 2048, 1024, b3, 1024, hB, 1024, hdr, nullptr, nullptr, Ppart);
        k_tailc<<<256, 256, 0, stream>>>(Ppart, b3, 1024, 4, hB, 1024, hdr);
    } else {
        k_gemm<128, 256, 8, false, true, false><<<dim3(4, 2), 512, 0, stream>>>(
            hA, 2048, Wt3, 2048, 1024, b3, 1024, hB, 1024, hdr, nullptr, nullptr, nullptr);
    }

    // L4: (Mp,1024) @ (1024,362->384), fused MSE -- all 128-tiles
    if (!merged) k_transpose<<<dim3(16, 12, 3), dim3(32, 8), 0, stream>>>(W4, Wt4, 1024, XD, 1024, 384);
    k_gemm<128, 128, 4, true, false, false><<<dim3(3, NTILES), 256, 0, stream>>>(
        hB, 1024, Wt4, 1024, 384, b4, XD, nullptr, 0, hdr, nextv, row_of, accum);

    k_final<<<1, 64, 0, stream>>>(hdr, (float*)d_out);
}